// Round 18
// baseline (10541.618 us; speedup 1.0000x reference)
//
#include <hip/hip_runtime.h>

#define TT   2048
#define NB   32
#define NI   512
#define NHID 512
#define NWG  32
#define KSL  16   // h-columns owned per workgroup

typedef float    f32x4 __attribute__((ext_vector_type(4)));
typedef _Float16 f16x8 __attribute__((ext_vector_type(8)));

// g_flags[w*16 + half*8] = t+1 when (block w, batch-half) h-slice stored (64B pad).
// [512]=xcc mask, [513]=arrival count.
__device__ __align__(256) unsigned int g_flags[576];
__device__ __align__(256) _Float16    g_hb0[NB * NHID];
__device__ __align__(256) _Float16    g_hb1[NB * NHID];
// Pre-packed input-side weight fragments: [w][mat(Wih r,z,n + Wd)][kc][lane][e]. 4MB.
__device__ __align__(256) _Float16    g_wfrag[NWG][4][16][64][8];

__device__ __forceinline__ f16x8 pack8(f32x4 a, f32x4 b) {
    f16x8 r;
    r[0] = (_Float16)a[0]; r[1] = (_Float16)a[1]; r[2] = (_Float16)a[2]; r[3] = (_Float16)a[3];
    r[4] = (_Float16)b[0]; r[5] = (_Float16)b[1]; r[6] = (_Float16)b[2]; r[7] = (_Float16)b[3];
    return r;
}

__device__ __forceinline__ unsigned int poll_load_nt(const unsigned int* p) {
    unsigned int v;
    asm volatile("global_load_dword %0, %1, off nt\n\ts_waitcnt vmcnt(0)"
                 : "=v"(v) : "v"(p) : "memory");
    return v;
}

extern "C" __global__ void init_flags_k() {
    for (int i = threadIdx.x; i < 576; i += 256) g_flags[i] = 0u;
}

extern "C" __global__ void pack_wfrag_k(const float* __restrict__ Wih,
                                        const float* __restrict__ Wd) {
    const int w    = blockIdx.x;
    const int tid  = threadIdx.x;
    const int lane = tid & 63;
    const int mat  = tid >> 6;           // 0..3
    const int r15  = lane & 15;
    const int g4   = lane >> 4;
    const float* src = (mat < 3) ? (Wih + (size_t)(mat * 512 + w * KSL + r15) * NI)
                                 : (Wd  + (size_t)(w * KSL + r15) * NI);
    #pragma unroll
    for (int kc = 0; kc < 16; ++kc) {
        const f32x4* p = (const f32x4*)(src + kc * 32 + g4 * 8);
        *(f16x8*)&g_wfrag[w][mat][kc][lane][0] = pack8(p[0], p[1]);
    }
}

// ABLATION: r16 worker bytes exactly, spinner waves REMOVED (4-wave 256-thr
// blocks, grid 256). Decides whether r14/r16's 1.8x came from extra-wave
// presence on the worker CUs (then ~19ms here, re-add r14 spinner blocks) or
// from the bundled worker changes: gi_lds padding (bank conflict 14.7M->2.1M),
// wfrag->global L2 streaming, out-ring removal (then ~10.4ms here and "heat"
// was an artifact; continue on the simpler kernel).
extern "C" __global__ void __launch_bounds__(256, 1)
gru_persist(const float* __restrict__ X, const float* __restrict__ h0,
            const float* __restrict__ Wih, const float* __restrict__ Whh,
            const float* __restrict__ bih, const float* __restrict__ bhh,
            const float* __restrict__ Wd,  const float* __restrict__ bd,
            float* __restrict__ out)
{
    if (blockIdx.x & 7) return;
    const int w  = blockIdx.x >> 3;
    const int ks = w * KSL;

    __shared__ _Float16 fragWhh[3][16][64][8];   // 48 KB
    __shared__ float    gi_lds[2][2][4][16][20]; // 20 KB, padded (2-way = free)
    __shared__ float    bias_h[3][KSL];
    __shared__ float    bias_i[4][KSL];
    __shared__ unsigned int seq[16];  // 0,1 prod_seq; 2,3 cons_seq
    __shared__ unsigned int fast_sh;
    volatile unsigned int* vseq = seq;

    const int tid  = threadIdx.x;
    const int lane = tid & 63;
    const int wv   = tid >> 6;
    const int half = wv & 1;
    const int isp  = wv >> 1;      // 0 = consumer, 1 = producer
    const int r15  = lane & 15;
    const int g4   = lane >> 4;

    if (tid < 16) seq[tid] = 0u;
    if (tid < KSL) {
        int k = ks + tid;
        bias_h[0][tid] = bhh[k];
        bias_h[1][tid] = bhh[512 + k];
        bias_h[2][tid] = bhh[1024 + k];
        bias_i[0][tid] = bih[k];
        bias_i[1][tid] = bih[512 + k];
        bias_i[2][tid] = bih[1024 + k];
        bias_i[3][tid] = bd[k];
    }
    // pack Whh fragments into LDS (one gate per wave, waves 0-2)
    if (wv < 3) {
        const float* src = Whh + (size_t)(wv * 512 + ks + r15) * NHID;
        #pragma unroll
        for (int kc = 0; kc < 16; ++kc) {
            const f32x4* p = (const f32x4*)(src + kc * 32 + g4 * 8);
            *(f16x8*)&fragWhh[wv][kc][lane][0] = pack8(p[0], p[1]);
        }
    }
    if (tid == 0) {
        unsigned int xcc;
        asm volatile("s_getreg_b32 %0, hwreg(HW_REG_XCC_ID, 0, 32)" : "=s"(xcc));
        unsigned int bit = 1u << (xcc & 7);
        unsigned int* mask  = g_flags + 512;
        unsigned int* count = g_flags + 513;
        unsigned int old = __hip_atomic_fetch_or(mask, bit, __ATOMIC_RELAXED,
                                                 __HIP_MEMORY_SCOPE_AGENT);
        asm volatile("" :: "v"(old));
        __hip_atomic_fetch_add(count, 1u, __ATOMIC_RELAXED, __HIP_MEMORY_SCOPE_AGENT);
        while (__hip_atomic_load(count, __ATOMIC_RELAXED,
                                 __HIP_MEMORY_SCOPE_AGENT) < NWG) { }
        unsigned int m = __hip_atomic_load(mask, __ATOMIC_RELAXED,
                                           __HIP_MEMORY_SCOPE_AGENT);
        fast_sh = ((m & (m - 1)) == 0) ? 1u : 0u;
    }
    __syncthreads();
    const bool fast = (fast_sh != 0);
    const int  bg   = half * 16 + r15;

    if (!isp) {
        // ================= CONSUMER (waves 0,1) =================
        __builtin_amdgcn_s_setprio(1);
        f32x4 hold = *(const f32x4*)(h0 + (size_t)bg * NHID + ks + g4 * 4);
        const f32x4 bhr = *(const f32x4*)&bias_h[0][g4 * 4];
        const f32x4 bhz = *(const f32x4*)&bias_h[1][g4 * 4];
        const f32x4 bhn = *(const f32x4*)&bias_h[2][g4 * 4];
        const f32x4 bir = *(const f32x4*)&bias_i[0][g4 * 4];
        const f32x4 biz = *(const f32x4*)&bias_i[1][g4 * 4];
        const f32x4 bin = *(const f32x4*)&bias_i[2][g4 * 4];
        const f32x4 bd4 = *(const f32x4*)&bias_i[3][g4 * 4];
        const float* h0row = h0 + (size_t)bg * NHID;

        #pragma unroll 1
        for (int t = 0; t < TT; ++t) {
            // -- 1. cross-block wait
            if (t > 0 && lane < NWG) {
                const unsigned int* fp = &g_flags[lane * 16 + half * 8];
                if (fast) { while (poll_load_nt(fp) < (unsigned)t) { } }
                else      { while (__hip_atomic_load(fp, __ATOMIC_RELAXED,
                                       __HIP_MEMORY_SCOPE_AGENT) < (unsigned)t) { } }
            }
            // -- 2. load h_t fragment
            f16x8 Bf[16];
            if (t == 0) {
                #pragma unroll
                for (int kc = 0; kc < 16; ++kc) {
                    const f32x4* p = (const f32x4*)(h0row + kc * 32 + g4 * 8);
                    Bf[kc] = pack8(p[0], p[1]);
                }
            } else {
                const _Float16* hrow = ((t & 1) ? g_hb1 : g_hb0) + (size_t)bg * NHID;
                if (fast) {
                    #pragma unroll
                    for (int kc = 0; kc < 16; ++kc) {
                        const _Float16* p = hrow + kc * 32 + g4 * 8;
                        asm volatile("global_load_dwordx4 %0, %1, off nt"
                                     : "=v"(Bf[kc]) : "v"(p));
                    }
                } else {
                    #pragma unroll
                    for (int kc = 0; kc < 16; ++kc) {
                        const _Float16* p = hrow + kc * 32 + g4 * 8;
                        asm volatile("global_load_dwordx4 %0, %1, off sc0 sc1"
                                     : "=v"(Bf[kc]) : "v"(p));
                    }
                }
                asm volatile("s_waitcnt vmcnt(0)" ::: "memory");
                __builtin_amdgcn_sched_barrier(0);
            }
            // -- 3. gh MFMA, Whh fragments streamed from LDS
            f32x4 a0 = {0.f,0.f,0.f,0.f}, a1 = a0, a2 = a0;
            #pragma unroll
            for (int kc = 0; kc < 16; ++kc) {
                f16x8 w0 = *(const f16x8*)&fragWhh[0][kc][lane][0];
                f16x8 w1 = *(const f16x8*)&fragWhh[1][kc][lane][0];
                f16x8 w2 = *(const f16x8*)&fragWhh[2][kc][lane][0];
                a0 = __builtin_amdgcn_mfma_f32_16x16x32_f16(w0, Bf[kc], a0, 0, 0, 0);
                a1 = __builtin_amdgcn_mfma_f32_16x16x32_f16(w1, Bf[kc], a1, 0, 0, 0);
                a2 = __builtin_amdgcn_mfma_f32_16x16x32_f16(w2, Bf[kc], a2, 0, 0, 0);
            }
            // -- 4. gi ready? read it, release the parity slot
            while (vseq[half] < (unsigned)(t + 1)) { }
            const int par = t & 1;
            f32x4 gr = *(const f32x4*)&gi_lds[par][half][0][r15][g4 * 4];
            f32x4 gz = *(const f32x4*)&gi_lds[par][half][1][r15][g4 * 4];
            f32x4 gn = *(const f32x4*)&gi_lds[par][half][2][r15][g4 * 4];
            f32x4 gd = *(const f32x4*)&gi_lds[par][half][3][r15][g4 * 4];
            asm volatile("s_waitcnt lgkmcnt(0)" ::: "memory");
            if (lane == 0) vseq[2 + half] = (unsigned)(t + 1);
            // -- 5. gates in-register
            f32x4 hn, o;
            #pragma unroll
            for (int i = 0; i < 4; ++i) {
                float rr = 1.f / (1.f + __expf(-((gr[i] + bir[i]) + (a0[i] + bhr[i]))));
                float zz = 1.f / (1.f + __expf(-((gz[i] + biz[i]) + (a1[i] + bhz[i]))));
                float aa = (gn[i] + bin[i]) + rr * (a2[i] + bhn[i]);
                float nn = 1.f - 2.f / (__expf(2.f * aa) + 1.f);
                hn[i] = (1.f - zz) * nn + zz * hold[i];
                o[i]  = hn[i] + gd[i] + bd4[i];
            }
            hold = hn;
            // -- 6. h broadcast store (8B), drain, publish flag
            union { _Float16 h[4]; unsigned long long u; } cv;
            cv.h[0] = (_Float16)hn[0]; cv.h[1] = (_Float16)hn[1];
            cv.h[2] = (_Float16)hn[2]; cv.h[3] = (_Float16)hn[3];
            _Float16* hw = (((t + 1) & 1) ? g_hb1 : g_hb0) + (size_t)bg * NHID + ks + g4 * 4;
            if (fast) {
                *(unsigned long long*)hw = cv.u;
            } else {
                asm volatile("global_store_dwordx2 %0, %1, off sc0 sc1"
                             :: "v"(hw), "v"(cv.u) : "memory");
            }
            asm volatile("s_waitcnt vmcnt(0)" ::: "memory");
            if (lane == 0) {
                unsigned int* fp = &g_flags[w * 16 + half * 8];
                if (fast) *(volatile unsigned int*)fp = (unsigned)(t + 1);
                else __hip_atomic_store(fp, (unsigned)(t + 1), __ATOMIC_RELAXED,
                                        __HIP_MEMORY_SCOPE_AGENT);
            }
            // -- 7. out store (post-flag; drains in next step's shadow)
            *(f32x4*)(out + (size_t)t * (NB * NHID) + (size_t)bg * NHID + ks + g4 * 4) = o;
        }
        // h_last
        *(f32x4*)(out + (size_t)TT * (NB * NHID) + (size_t)bg * NHID + ks + g4 * 4) = hold;
    } else {
        // ================= PRODUCER (waves 2,3) =================
        __builtin_amdgcn_s_setprio(1);
        const float* Xrow = X + (size_t)bg * NI;

        #pragma unroll 1
        for (int tp = 0; tp < TT; ++tp) {
            while ((int)vseq[2 + half] < tp - 1) { }   // 2-deep gi throttle
            const float* xp = Xrow + (size_t)tp * (NB * NI);
            f16x8 Bf[16];
            #pragma unroll
            for (int kc = 0; kc < 16; ++kc) {
                const f32x4* p = (const f32x4*)(xp + kc * 32 + g4 * 8);
                Bf[kc] = pack8(p[0], p[1]);
            }
            f32x4 acc[4];
            #pragma unroll
            for (int q = 0; q < 4; ++q) acc[q] = (f32x4){0.f, 0.f, 0.f, 0.f};
            #pragma unroll
            for (int mat = 0; mat < 4; ++mat) {
                f16x8 wb[16];
                #pragma unroll
                for (int kc = 0; kc < 16; ++kc)
                    wb[kc] = *(const f16x8*)&g_wfrag[w][mat][kc][lane][0];
                #pragma unroll
                for (int kc = 0; kc < 16; ++kc)
                    acc[mat] = __builtin_amdgcn_mfma_f32_16x16x32_f16(wb[kc], Bf[kc], acc[mat], 0, 0, 0);
            }
            const int par = tp & 1;
            *(f32x4*)&gi_lds[par][half][0][r15][g4 * 4] = acc[0];
            *(f32x4*)&gi_lds[par][half][1][r15][g4 * 4] = acc[1];
            *(f32x4*)&gi_lds[par][half][2][r15][g4 * 4] = acc[2];
            *(f32x4*)&gi_lds[par][half][3][r15][g4 * 4] = acc[3];
            asm volatile("s_waitcnt lgkmcnt(0)" ::: "memory");
            if (lane == 0) vseq[half] = (unsigned)(tp + 1);
        }
    }
}

extern "C" void kernel_launch(void* const* d_in, const int* in_sizes, int n_in,
                              void* d_out, int out_size, void* d_ws, size_t ws_size,
                              hipStream_t stream) {
    const float* X   = (const float*)d_in[0];
    const float* h0  = (const float*)d_in[1];
    const float* Wih = (const float*)d_in[2];
    const float* Whh = (const float*)d_in[3];
    const float* bih = (const float*)d_in[4];
    const float* bhh = (const float*)d_in[5];
    const float* Wd  = (const float*)d_in[6];
    const float* bd  = (const float*)d_in[7];
    float* out = (float*)d_out;

    init_flags_k<<<dim3(1), dim3(256), 0, stream>>>();
    pack_wfrag_k<<<dim3(NWG), dim3(256), 0, stream>>>(Wih, Wd);

    gru_persist<<<dim3(256), dim3(256), 0, stream>>>(
        X, h0, Wih, Whh, bih, bhh, Wd, bd, out);
}

// Round 19
// 10281.929 us; speedup vs baseline: 1.0253x; 1.0253x over previous
//
#include <hip/hip_runtime.h>

#define TT   2048
#define NB   32
#define NI   512
#define NHID 512
#define NWG  32
#define KSL  16   // h-columns owned per workgroup

typedef float    f32x4 __attribute__((ext_vector_type(4)));
typedef _Float16 f16x8 __attribute__((ext_vector_type(8)));

// g_flags[w*16 + half*8] = t+1 when (block w, batch-half) h-slice stored (64B pad).
// [512]=xcc mask, [513]=arrival count.
__device__ __align__(256) unsigned int g_flags[576];
__device__ __align__(256) _Float16    g_hb0[NB * NHID];
__device__ __align__(256) _Float16    g_hb1[NB * NHID];
// Pre-packed input-side weight fragments: [w][mat(Wih r,z,n + Wd)][kc][lane][e]. 4MB.
__device__ __align__(256) _Float16    g_wfrag[NWG][4][16][64][8];

__device__ __forceinline__ f16x8 pack8(f32x4 a, f32x4 b) {
    f16x8 r;
    r[0] = (_Float16)a[0]; r[1] = (_Float16)a[1]; r[2] = (_Float16)a[2]; r[3] = (_Float16)a[3];
    r[4] = (_Float16)b[0]; r[5] = (_Float16)b[1]; r[6] = (_Float16)b[2]; r[7] = (_Float16)b[3];
    return r;
}

__device__ __forceinline__ unsigned int poll_load_nt(const unsigned int* p) {
    unsigned int v;
    asm volatile("global_load_dword %0, %1, off nt\n\ts_waitcnt vmcnt(0)"
                 : "=v"(v) : "v"(p) : "memory");
    return v;
}

extern "C" __global__ void init_flags_k() {
    for (int i = threadIdx.x; i < 576; i += 256) g_flags[i] = 0u;
}

extern "C" __global__ void pack_wfrag_k(const float* __restrict__ Wih,
                                        const float* __restrict__ Wd) {
    const int w    = blockIdx.x;
    const int tid  = threadIdx.x;
    const int lane = tid & 63;
    const int mat  = tid >> 6;           // 0..3
    const int r15  = lane & 15;
    const int g4   = lane >> 4;
    const float* src = (mat < 3) ? (Wih + (size_t)(mat * 512 + w * KSL + r15) * NI)
                                 : (Wd  + (size_t)(w * KSL + r15) * NI);
    #pragma unroll
    for (int kc = 0; kc < 16; ++kc) {
        const f32x4* p = (const f32x4*)(src + kc * 32 + g4 * 8);
        *(f16x8*)&g_wfrag[w][mat][kc][lane][0] = pack8(p[0], p[1]);
    }
}

// r18 worker + DIAGNOSTIC INSTRUMENTATION + depth-4 gi buffer.
// r18 counters: step = ~12.7k cycles at ~full clock, only ~1k busy -> ~11.7k
// stall somewhere in {consumer-waits-gi, producer-waits-throttle, flag-poll,
// in-phase memory latency}. Readout channels: consumer gi-wait burns VALU FMA
// (-> VALUBusy, dVALU ~= 6.25% * f_cons_wait), producer throttle-wait burns
// dummy MFMA (-> MfmaUtil, dMfma ~= 6.25% * f_prod_wait). Flag-poll clean.
// gi depth 2->4 (throttle tp-3) hides producer lookahead latency if that was
// the limiter.
extern "C" __global__ void __launch_bounds__(256, 1)
gru_persist(const float* __restrict__ X, const float* __restrict__ h0,
            const float* __restrict__ Wih, const float* __restrict__ Whh,
            const float* __restrict__ bih, const float* __restrict__ bhh,
            const float* __restrict__ Wd,  const float* __restrict__ bd,
            float* __restrict__ out)
{
    if (blockIdx.x & 7) return;
    const int w  = blockIdx.x >> 3;
    const int ks = w * KSL;

    __shared__ _Float16 fragWhh[3][16][64][8];   // 48 KB
    __shared__ float    gi_lds[4][2][4][16][20]; // 40 KB, 4-deep, padded
    __shared__ float    bias_h[3][KSL];
    __shared__ float    bias_i[4][KSL];
    __shared__ unsigned int seq[16];  // 0,1 prod_seq; 2,3 cons_seq
    __shared__ unsigned int fast_sh;
    volatile unsigned int* vseq = seq;

    const int tid  = threadIdx.x;
    const int lane = tid & 63;
    const int wv   = tid >> 6;
    const int half = wv & 1;
    const int isp  = wv >> 1;      // 0 = consumer, 1 = producer
    const int r15  = lane & 15;
    const int g4   = lane >> 4;

    if (tid < 16) seq[tid] = 0u;
    if (tid < KSL) {
        int k = ks + tid;
        bias_h[0][tid] = bhh[k];
        bias_h[1][tid] = bhh[512 + k];
        bias_h[2][tid] = bhh[1024 + k];
        bias_i[0][tid] = bih[k];
        bias_i[1][tid] = bih[512 + k];
        bias_i[2][tid] = bih[1024 + k];
        bias_i[3][tid] = bd[k];
    }
    // pack Whh fragments into LDS (one gate per wave, waves 0-2)
    if (wv < 3) {
        const float* src = Whh + (size_t)(wv * 512 + ks + r15) * NHID;
        #pragma unroll
        for (int kc = 0; kc < 16; ++kc) {
            const f32x4* p = (const f32x4*)(src + kc * 32 + g4 * 8);
            *(f16x8*)&fragWhh[wv][kc][lane][0] = pack8(p[0], p[1]);
        }
    }
    if (tid == 0) {
        unsigned int xcc;
        asm volatile("s_getreg_b32 %0, hwreg(HW_REG_XCC_ID, 0, 32)" : "=s"(xcc));
        unsigned int bit = 1u << (xcc & 7);
        unsigned int* mask  = g_flags + 512;
        unsigned int* count = g_flags + 513;
        unsigned int old = __hip_atomic_fetch_or(mask, bit, __ATOMIC_RELAXED,
                                                 __HIP_MEMORY_SCOPE_AGENT);
        asm volatile("" :: "v"(old));
        __hip_atomic_fetch_add(count, 1u, __ATOMIC_RELAXED, __HIP_MEMORY_SCOPE_AGENT);
        while (__hip_atomic_load(count, __ATOMIC_RELAXED,
                                 __HIP_MEMORY_SCOPE_AGENT) < NWG) { }
        unsigned int m = __hip_atomic_load(mask, __ATOMIC_RELAXED,
                                           __HIP_MEMORY_SCOPE_AGENT);
        fast_sh = ((m & (m - 1)) == 0) ? 1u : 0u;
    }
    __syncthreads();
    const bool fast = (fast_sh != 0);
    const int  bg   = half * 16 + r15;

    if (!isp) {
        // ================= CONSUMER (waves 0,1) =================
        __builtin_amdgcn_s_setprio(1);
        f32x4 hold = *(const f32x4*)(h0 + (size_t)bg * NHID + ks + g4 * 4);
        const f32x4 bhr = *(const f32x4*)&bias_h[0][g4 * 4];
        const f32x4 bhz = *(const f32x4*)&bias_h[1][g4 * 4];
        const f32x4 bhn = *(const f32x4*)&bias_h[2][g4 * 4];
        const f32x4 bir = *(const f32x4*)&bias_i[0][g4 * 4];
        const f32x4 biz = *(const f32x4*)&bias_i[1][g4 * 4];
        const f32x4 bin = *(const f32x4*)&bias_i[2][g4 * 4];
        const f32x4 bd4 = *(const f32x4*)&bias_i[3][g4 * 4];
        const float* h0row = h0 + (size_t)bg * NHID;

        // VALU-burn state (diagnostic channel: consumer gi-wait -> VALUBusy)
        float s0 = 1.0f + 0.5f * (float)tid, s1 = s0 + .3f, s2 = s0 + .6f, s3 = s0 + .9f;
        const float mm = 1.0000001f, cc = 1.0e-7f;

        #pragma unroll 1
        for (int t = 0; t < TT; ++t) {
            // -- 1. cross-block wait (clean: no burn, known ~1% from r9)
            if (t > 0 && lane < NWG) {
                const unsigned int* fp = &g_flags[lane * 16 + half * 8];
                if (fast) { while (poll_load_nt(fp) < (unsigned)t) { } }
                else      { while (__hip_atomic_load(fp, __ATOMIC_RELAXED,
                                       __HIP_MEMORY_SCOPE_AGENT) < (unsigned)t) { } }
            }
            // -- 2. load h_t fragment
            f16x8 Bf[16];
            if (t == 0) {
                #pragma unroll
                for (int kc = 0; kc < 16; ++kc) {
                    const f32x4* p = (const f32x4*)(h0row + kc * 32 + g4 * 8);
                    Bf[kc] = pack8(p[0], p[1]);
                }
            } else {
                const _Float16* hrow = ((t & 1) ? g_hb1 : g_hb0) + (size_t)bg * NHID;
                if (fast) {
                    #pragma unroll
                    for (int kc = 0; kc < 16; ++kc) {
                        const _Float16* p = hrow + kc * 32 + g4 * 8;
                        asm volatile("global_load_dwordx4 %0, %1, off nt"
                                     : "=v"(Bf[kc]) : "v"(p));
                    }
                } else {
                    #pragma unroll
                    for (int kc = 0; kc < 16; ++kc) {
                        const _Float16* p = hrow + kc * 32 + g4 * 8;
                        asm volatile("global_load_dwordx4 %0, %1, off sc0 sc1"
                                     : "=v"(Bf[kc]) : "v"(p));
                    }
                }
                asm volatile("s_waitcnt vmcnt(0)" ::: "memory");
                __builtin_amdgcn_sched_barrier(0);
            }
            // -- 3. gh MFMA, Whh fragments streamed from LDS
            f32x4 a0 = {0.f,0.f,0.f,0.f}, a1 = a0, a2 = a0;
            #pragma unroll
            for (int kc = 0; kc < 16; ++kc) {
                f16x8 w0 = *(const f16x8*)&fragWhh[0][kc][lane][0];
                f16x8 w1 = *(const f16x8*)&fragWhh[1][kc][lane][0];
                f16x8 w2 = *(const f16x8*)&fragWhh[2][kc][lane][0];
                a0 = __builtin_amdgcn_mfma_f32_16x16x32_f16(w0, Bf[kc], a0, 0, 0, 0);
                a1 = __builtin_amdgcn_mfma_f32_16x16x32_f16(w1, Bf[kc], a1, 0, 0, 0);
                a2 = __builtin_amdgcn_mfma_f32_16x16x32_f16(w2, Bf[kc], a2, 0, 0, 0);
            }
            // -- 4. gi ready? (INSTRUMENTED wait: VALU FMA burn)
            while (vseq[half] < (unsigned)(t + 1)) {
                #pragma unroll
                for (int i = 0; i < 8; ++i) {
                    s0 = __builtin_fmaf(s0, mm, cc); s1 = __builtin_fmaf(s1, mm, cc);
                    s2 = __builtin_fmaf(s2, mm, cc); s3 = __builtin_fmaf(s3, mm, cc);
                }
            }
            const int par = t & 3;
            f32x4 gr = *(const f32x4*)&gi_lds[par][half][0][r15][g4 * 4];
            f32x4 gz = *(const f32x4*)&gi_lds[par][half][1][r15][g4 * 4];
            f32x4 gn = *(const f32x4*)&gi_lds[par][half][2][r15][g4 * 4];
            f32x4 gd = *(const f32x4*)&gi_lds[par][half][3][r15][g4 * 4];
            asm volatile("s_waitcnt lgkmcnt(0)" ::: "memory");
            if (lane == 0) vseq[2 + half] = (unsigned)(t + 1);
            // -- 5. gates in-register
            f32x4 hn, o;
            #pragma unroll
            for (int i = 0; i < 4; ++i) {
                float rr = 1.f / (1.f + __expf(-((gr[i] + bir[i]) + (a0[i] + bhr[i]))));
                float zz = 1.f / (1.f + __expf(-((gz[i] + biz[i]) + (a1[i] + bhz[i]))));
                float aa = (gn[i] + bin[i]) + rr * (a2[i] + bhn[i]);
                float nn = 1.f - 2.f / (__expf(2.f * aa) + 1.f);
                hn[i] = (1.f - zz) * nn + zz * hold[i];
                o[i]  = hn[i] + gd[i] + bd4[i];
            }
            hold = hn;
            // -- 6. h broadcast store (8B), drain, publish flag
            union { _Float16 h[4]; unsigned long long u; } cv;
            cv.h[0] = (_Float16)hn[0]; cv.h[1] = (_Float16)hn[1];
            cv.h[2] = (_Float16)hn[2]; cv.h[3] = (_Float16)hn[3];
            _Float16* hw = (((t + 1) & 1) ? g_hb1 : g_hb0) + (size_t)bg * NHID + ks + g4 * 4;
            if (fast) {
                *(unsigned long long*)hw = cv.u;
            } else {
                asm volatile("global_store_dwordx2 %0, %1, off sc0 sc1"
                             :: "v"(hw), "v"(cv.u) : "memory");
            }
            asm volatile("s_waitcnt vmcnt(0)" ::: "memory");
            if (lane == 0) {
                unsigned int* fp = &g_flags[w * 16 + half * 8];
                if (fast) *(volatile unsigned int*)fp = (unsigned)(t + 1);
                else __hip_atomic_store(fp, (unsigned)(t + 1), __ATOMIC_RELAXED,
                                        __HIP_MEMORY_SCOPE_AGENT);
            }
            // -- 7. out store (post-flag; drains in next step's shadow)
            *(f32x4*)(out + (size_t)t * (NB * NHID) + (size_t)bg * NHID + ks + g4 * 4) = o;
        }
        // h_last
        *(f32x4*)(out + (size_t)TT * (NB * NHID) + (size_t)bg * NHID + ks + g4 * 4) = hold;
        asm volatile("" :: "v"(s0), "v"(s1), "v"(s2), "v"(s3));
    } else {
        // ================= PRODUCER (waves 2,3) =================
        __builtin_amdgcn_s_setprio(1);
        const float* Xrow = X + (size_t)bg * NI;

        // MFMA-burn state (diagnostic channel: producer wait -> MfmaUtil)
        f16x8 zf = {};
        f32x4 accd = {0.f, 0.f, 0.f, 0.f};

        #pragma unroll 1
        for (int tp = 0; tp < TT; ++tp) {
            // 4-deep gi throttle (INSTRUMENTED wait: dummy MFMA burn)
            while ((int)vseq[2 + half] < tp - 3) {
                accd = __builtin_amdgcn_mfma_f32_16x16x32_f16(zf, zf, accd, 0, 0, 0);
                accd = __builtin_amdgcn_mfma_f32_16x16x32_f16(zf, zf, accd, 0, 0, 0);
                accd = __builtin_amdgcn_mfma_f32_16x16x32_f16(zf, zf, accd, 0, 0, 0);
                accd = __builtin_amdgcn_mfma_f32_16x16x32_f16(zf, zf, accd, 0, 0, 0);
            }
            const float* xp = Xrow + (size_t)tp * (NB * NI);
            f16x8 Bf[16];
            #pragma unroll
            for (int kc = 0; kc < 16; ++kc) {
                const f32x4* p = (const f32x4*)(xp + kc * 32 + g4 * 8);
                Bf[kc] = pack8(p[0], p[1]);
            }
            f32x4 acc[4];
            #pragma unroll
            for (int q = 0; q < 4; ++q) acc[q] = (f32x4){0.f, 0.f, 0.f, 0.f};
            #pragma unroll
            for (int mat = 0; mat < 4; ++mat) {
                f16x8 wb[16];
                #pragma unroll
                for (int kc = 0; kc < 16; ++kc)
                    wb[kc] = *(const f16x8*)&g_wfrag[w][mat][kc][lane][0];
                #pragma unroll
                for (int kc = 0; kc < 16; ++kc)
                    acc[mat] = __builtin_amdgcn_mfma_f32_16x16x32_f16(wb[kc], Bf[kc], acc[mat], 0, 0, 0);
            }
            const int par = tp & 3;
            *(f32x4*)&gi_lds[par][half][0][r15][g4 * 4] = acc[0];
            *(f32x4*)&gi_lds[par][half][1][r15][g4 * 4] = acc[1];
            *(f32x4*)&gi_lds[par][half][2][r15][g4 * 4] = acc[2];
            *(f32x4*)&gi_lds[par][half][3][r15][g4 * 4] = acc[3];
            asm volatile("s_waitcnt lgkmcnt(0)" ::: "memory");
            if (lane == 0) vseq[half] = (unsigned)(tp + 1);
        }
        asm volatile("" :: "v"(accd[0]), "v"(accd[1]), "v"(accd[2]), "v"(accd[3]));
    }
}

extern "C" void kernel_launch(void* const* d_in, const int* in_sizes, int n_in,
                              void* d_out, int out_size, void* d_ws, size_t ws_size,
                              hipStream_t stream) {
    const float* X   = (const float*)d_in[0];
    const float* h0  = (const float*)d_in[1];
    const float* Wih = (const float*)d_in[2];
    const float* Whh = (const float*)d_in[3];
    const float* bih = (const float*)d_in[4];
    const float* bhh = (const float*)d_in[5];
    const float* Wd  = (const float*)d_in[6];
    const float* bd  = (const float*)d_in[7];
    float* out = (float*)d_out;

    init_flags_k<<<dim3(1), dim3(256), 0, stream>>>();
    pack_wfrag_k<<<dim3(NWG), dim3(256), 0, stream>>>(Wih, Wd);

    gru_persist<<<dim3(256), dim3(256), 0, stream>>>(
        X, h0, Wih, Whh, bih, bhh, Wd, bd, out);
}